// Round 1
// 274.712 us; speedup vs baseline: 1.0471x; 1.0471x over previous
//
#include <hip/hip_runtime.h>
#include <math.h>

#define BB 8
#define SS 2048
#define EE 1024
#define HH 64
#define MM (BB * SS)   // 16384 rows

typedef unsigned short u16;
typedef __attribute__((ext_vector_type(8))) short short8;   // 8 x bf16
typedef __attribute__((ext_vector_type(4))) float floatx4;  // mfma C/D

__device__ __forceinline__ u16 f2bf(float f) {
    union { float f; unsigned u; } a; a.f = f;
    unsigned r = a.u + 0x7fffu + ((a.u >> 16) & 1u);   // RNE
    return (u16)(r >> 16);
}

// Split two fp32 into packed bf16 hi (truncated) and bf16 lo (residual, truncated).
// hi+lo reproduces fp32 to ~2^-16 relative.
__device__ __forceinline__ void split2(float f0, float f1, unsigned& hp, unsigned& lp) {
    union { float f; unsigned u; } a0, a1, h0, h1, l0, l1;
    a0.f = f0; a1.f = f1;
    h0.u = a0.u & 0xffff0000u;
    h1.u = a1.u & 0xffff0000u;
    l0.f = f0 - h0.f;
    l1.f = f1 - h1.f;
    hp = __builtin_amdgcn_perm(a1.u, a0.u, 0x07060302u);  // [hi16(f1)|hi16(f0)]
    lp = __builtin_amdgcn_perm(l1.u, l0.u, 0x07060302u);
}

// ---------------------------------------------------------------------------
// Projection GEMM via bf16 MFMA + hi/lo compensation (3 passes).
// out[M x 64] = A[M x 1024] @ W[1024 x 64] + b.
// v2: A fragments loaded GLOBAL->REG directly (no LDS for A; the MFMA A-frag
//     for lane (n,g) is 8 contiguous floats of row n). Only W is staged in
//     LDS (needs transpose), double-buffered. 64 rows/block, grid 768 blocks
//     -> 3 blocks/CU, 12 waves/CU (was 1.5 blocks/CU, LDS-capped).
// Block 256 thr = 4 waves; wave w -> rows [w*16, w*16+16) = 1 m-tile x 4 n-tiles.
// ---------------------------------------------------------------------------
#define BMROWS 64
#define NCHUNK (EE / 64)

__device__ __forceinline__ void stage_w(const float4* wv, int wk, int wn,
                                        u16 (*__restrict__ wh)[72],
                                        u16 (*__restrict__ wl)[72]) {
    #pragma unroll
    for (int j = 0; j < 4; ++j) {
        const float e0 = (&wv[0].x)[j], e1 = (&wv[1].x)[j],
                    e2 = (&wv[2].x)[j], e3 = (&wv[3].x)[j];
        unsigned hp0, lp0, hp1, lp1;
        split2(e0, e1, hp0, lp0);
        split2(e2, e3, hp1, lp1);
        uint2 h2 = {hp0, hp1};
        uint2 l2 = {lp0, lp1};
        *(uint2*)&wh[wn + j][wk] = h2;
        *(uint2*)&wl[wn + j][wk] = l2;
    }
}

__global__ __launch_bounds__(256) void proj_mfma(
    const float* __restrict__ A0, const float* __restrict__ A1, const float* __restrict__ A2,
    const float* __restrict__ W0, const float* __restrict__ W1, const float* __restrict__ W2,
    const float* __restrict__ b0, const float* __restrict__ b1, const float* __restrict__ b2,
    u16* __restrict__ o0, u16* __restrict__ o1, u16* __restrict__ o2)
{
    const int which = blockIdx.y;
    const float* __restrict__ A    = (which == 0) ? A0 : (which == 1) ? A1 : A2;
    const float* __restrict__ W    = (which == 0) ? W0 : (which == 1) ? W1 : W2;
    const float* __restrict__ bias = (which == 0) ? b0 : (which == 1) ? b1 : b2;
    u16* __restrict__ out          = (which == 0) ? o0 : (which == 1) ? o1 : o2;

    // stride 72 shorts = 144 B: row r starts at bank 4r%32 -> 2-way aliasing (free)
    __shared__ __align__(16) u16 Wh[2][64][72], Wl[2][64][72];   // 36864 B total

    const int tid  = threadIdx.x;
    const int lane = tid & 63;
    const int wave = tid >> 6;
    const int n    = lane & 15;
    const int g    = lane >> 4;
    const int row0 = blockIdx.x * BMROWS;

    // A fragment source: row (row0 + wave*16 + n), 8 contiguous floats at g*8
    const float* __restrict__ ap = A + (size_t)(row0 + wave * 16 + n) * EE + g * 8;

    // W staging assignment: thread reads W[wk..wk+3][wn..wn+3], writes transposed
    const int wk = (tid >> 4) * 4;       // k rows
    const int wn = (tid & 15) * 4;       // n cols

    floatx4 acc[4];
    #pragma unroll
    for (int nt = 0; nt < 4; ++nt) acc[nt] = (floatx4){0.f, 0.f, 0.f, 0.f};

    // ---- prologue: chunk 0 of W -> LDS buf 0, chunk 0 of A -> regs --------
    float4 wv[4];
    #pragma unroll
    for (int i = 0; i < 4; ++i)
        wv[i] = *(const float4*)&W[(size_t)(wk + i) * HH + wn];

    float4 av[4];   // [ks*2 + half]: ks*32 + g*8 (+4)
    av[0] = *(const float4*)(ap + 0);
    av[1] = *(const float4*)(ap + 4);
    av[2] = *(const float4*)(ap + 32);
    av[3] = *(const float4*)(ap + 36);

    stage_w(wv, wk, wn, Wh[0], Wl[0]);
    __syncthreads();

    for (int t = 0; t < NCHUNK; ++t) {
        const int cur = t & 1;

        // current A chunk -> local copy; issue next chunk's A + W loads
        float4 ac[4];
        #pragma unroll
        for (int i = 0; i < 4; ++i) ac[i] = av[i];

        if (t + 1 < NCHUNK) {
            const float* apn = ap + (t + 1) * 64;
            av[0] = *(const float4*)(apn + 0);
            av[1] = *(const float4*)(apn + 4);
            av[2] = *(const float4*)(apn + 32);
            av[3] = *(const float4*)(apn + 36);
            #pragma unroll
            for (int i = 0; i < 4; ++i)
                wv[i] = *(const float4*)&W[(size_t)((t + 1) * 64 + wk + i) * HH + wn];
        }

        // ---- compute: 2 k-steps of 32, in-register hi/lo split -----------
        #pragma unroll
        for (int ks = 0; ks < 2; ++ks) {
            unsigned hp0, lp0, hp1, lp1, hp2, lp2, hp3, lp3;
            split2(ac[ks * 2].x,     ac[ks * 2].y,     hp0, lp0);
            split2(ac[ks * 2].z,     ac[ks * 2].w,     hp1, lp1);
            split2(ac[ks * 2 + 1].x, ac[ks * 2 + 1].y, hp2, lp2);
            split2(ac[ks * 2 + 1].z, ac[ks * 2 + 1].w, hp3, lp3);
            union { uint4 u; short8 s; } ch, cl;
            ch.u = (uint4){hp0, hp1, hp2, hp3};
            cl.u = (uint4){lp0, lp1, lp2, lp3};
            const short8 ah = ch.s, al = cl.s;

            #pragma unroll
            for (int nt = 0; nt < 4; ++nt) {
                const short8 whf = *(const short8*)&Wh[cur][nt * 16 + n][ks * 32 + g * 8];
                const short8 wlf = *(const short8*)&Wl[cur][nt * 16 + n][ks * 32 + g * 8];
                acc[nt] = __builtin_amdgcn_mfma_f32_16x16x32_bf16(ah, whf, acc[nt], 0, 0, 0);
                acc[nt] = __builtin_amdgcn_mfma_f32_16x16x32_bf16(al, whf, acc[nt], 0, 0, 0);
                acc[nt] = __builtin_amdgcn_mfma_f32_16x16x32_bf16(ah, wlf, acc[nt], 0, 0, 0);
            }
        }

        // ---- write next W chunk into the other buffer --------------------
        if (t + 1 < NCHUNK)
            stage_w(wv, wk, wn, Wh[cur ^ 1], Wl[cur ^ 1]);
        __syncthreads();
    }

    // ---- epilogue: bias + bf16 store -------------------------------------
    #pragma unroll
    for (int nt = 0; nt < 4; ++nt) {
        const float bv = bias[nt * 16 + n];
        #pragma unroll
        for (int r = 0; r < 4; ++r) {
            const int row = row0 + wave * 16 + g * 4 + r;
            out[(size_t)row * HH + nt * 16 + n] = f2bf(acc[nt][r] + bv);
        }
    }
}

// ---------------------------------------------------------------------------
// MFMA flash attention, double-buffered 64-key tiles, 1 barrier/iter.
// Block 256 thr = 4 waves: wq = wave&1 (16-q tile), ks = wave>>1 (32-key half).
// Grid (64, 8). Next tile loaded to regs before compute, written after.
// ---------------------------------------------------------------------------
__global__ __launch_bounds__(256) void flash_mfma(
    const u16* __restrict__ qp, const u16* __restrict__ kp,
    const u16* __restrict__ vp, float* __restrict__ out)
{
    __shared__ __align__(16) u16 Ks[2][64 * 64];   // row j: 8 chunks, chunk cs at cs^(j&7)
    __shared__ __align__(16) u16 Vt[2][64 * 64];   // row h: 8 j-chunks, chunk cj at cj^(h&7)
    __shared__ __align__(16) u16 Pw[4][16 * 72];

    const int b    = blockIdx.y;
    const int q0   = blockIdx.x * 32;
    const int tid  = threadIdx.x;
    const int lane = tid & 63;
    const int wave = tid >> 6;
    const int wq   = wave & 1;
    const int ks   = wave >> 1;
    const int n    = lane & 15;
    const int g    = lane >> 4;

    const u16* qrow = qp + ((size_t)b * SS + q0 + wq * 16 + n) * HH;
    const short8 qa0 = *(const short8*)(qrow + g * 8);
    const short8 qa1 = *(const short8*)(qrow + 32 + g * 8);

    floatx4 Oa[4];
    #pragma unroll
    for (int ht = 0; ht < 4; ++ht) Oa[ht] = (floatx4){0.f, 0.f, 0.f, 0.f};
    float m_i[4], l_i[4];
    #pragma unroll
    for (int r = 0; r < 4; ++r) { m_i[r] = -1e30f; l_i[r] = 0.f; }

    const u16* kb = kp + (size_t)b * SS * HH;
    const u16* vb = vp + (size_t)b * SS * HH;

    // staging indices (tid-only)
    const int jK0 = tid >> 3, jK1 = 32 + (tid >> 3), cs = tid & 7;
    const int jV  = (tid & 15) * 4, hV = (tid >> 4) * 4;

    short8  kr0, kr1;
    ushort4 vr0, vr1, vr2, vr3;

    // ---- prologue: stage tile 0 into buf 0 --------------------------------
    kr0 = *(const short8*)(kb + (size_t)jK0 * HH + cs * 8);
    kr1 = *(const short8*)(kb + (size_t)jK1 * HH + cs * 8);
    vr0 = *(const ushort4*)(vb + (size_t)(jV + 0) * HH + hV);
    vr1 = *(const ushort4*)(vb + (size_t)(jV + 1) * HH + hV);
    vr2 = *(const ushort4*)(vb + (size_t)(jV + 2) * HH + hV);
    vr3 = *(const ushort4*)(vb + (size_t)(jV + 3) * HH + hV);
    {
        *(short8*)&Ks[0][jK0 * 64 + ((cs ^ (jK0 & 7)) << 3)] = kr0;
        *(short8*)&Ks[0][jK1 * 64 + ((cs ^ (jK1 & 7)) << 3)] = kr1;
        const u16* a0 = (const u16*)&vr0; const u16* a1 = (const u16*)&vr1;
        const u16* a2 = (const u16*)&vr2; const u16* a3 = (const u16*)&vr3;
        #pragma unroll
        for (int i = 0; i < 4; ++i) {
            const int h = hV + i;
            ushort4 w; w.x = a0[i]; w.y = a1[i]; w.z = a2[i]; w.w = a3[i];
            *(ushort4*)((char*)&Vt[0][0] + h * 128 + (((jV >> 3) ^ (h & 7)) << 4) + ((jV & 4) << 1)) = w;
        }
    }
    __syncthreads();

    for (int t = 0; t < SS / 64; ++t) {
        const int cur = t & 1;

        // ---- issue next tile's global loads (latency hides under compute) --
        if (t + 1 < SS / 64) {
            const size_t kt = (size_t)(t + 1) * 64;
            kr0 = *(const short8*)(kb + (kt + jK0) * HH + cs * 8);
            kr1 = *(const short8*)(kb + (kt + jK1) * HH + cs * 8);
            vr0 = *(const ushort4*)(vb + (kt + jV + 0) * HH + hV);
            vr1 = *(const ushort4*)(vb + (kt + jV + 1) * HH + hV);
            vr2 = *(const ushort4*)(vb + (kt + jV + 2) * HH + hV);
            vr3 = *(const ushort4*)(vb + (kt + jV + 3) * HH + hV);
        }

        // ---- QK^T: S[16 q][32 keys] (my half) ------------------------------
        floatx4 S[2];
        #pragma unroll
        for (int nt = 0; nt < 2; ++nt) {
            const int j = ks * 32 + nt * 16 + n;
            const short8 kf0 = *(const short8*)&Ks[cur][j * 64 + (((0 + g) ^ (j & 7)) << 3)];
            const short8 kf1 = *(const short8*)&Ks[cur][j * 64 + (((4 + g) ^ (j & 7)) << 3)];
            floatx4 a = (floatx4){0.f, 0.f, 0.f, 0.f};
            a = __builtin_amdgcn_mfma_f32_16x16x32_bf16(qa0, kf0, a, 0, 0, 0);
            a = __builtin_amdgcn_mfma_f32_16x16x32_bf16(qa1, kf1, a, 0, 0, 0);
            S[nt] = a;
        }

        // ---- online softmax ------------------------------------------------
        float mx[4];
        #pragma unroll
        for (int r = 0; r < 4; ++r) mx[r] = -1e30f;
        #pragma unroll
        for (int nt = 0; nt < 2; ++nt)
            #pragma unroll
            for (int r = 0; r < 4; ++r) {
                S[nt][r] *= 0.125f;
                mx[r] = fmaxf(mx[r], S[nt][r]);
            }
        #pragma unroll
        for (int off = 8; off >= 1; off >>= 1)
            #pragma unroll
            for (int r = 0; r < 4; ++r)
                mx[r] = fmaxf(mx[r], __shfl_xor(mx[r], off, 64));

        float alpha[4], ps[4];
        #pragma unroll
        for (int r = 0; r < 4; ++r) {
            const float Mn = fmaxf(m_i[r], mx[r]);
            alpha[r] = __expf(m_i[r] - Mn);
            m_i[r]   = Mn;
            ps[r]    = 0.f;
        }
        float p[2][4];
        #pragma unroll
        for (int nt = 0; nt < 2; ++nt)
            #pragma unroll
            for (int r = 0; r < 4; ++r) {
                p[nt][r] = __expf(S[nt][r] - m_i[r]);
                ps[r] += p[nt][r];
            }
        #pragma unroll
        for (int off = 8; off >= 1; off >>= 1)
            #pragma unroll
            for (int r = 0; r < 4; ++r)
                ps[r] += __shfl_xor(ps[r], off, 64);
        #pragma unroll
        for (int r = 0; r < 4; ++r) l_i[r] = l_i[r] * alpha[r] + ps[r];
        #pragma unroll
        for (int ht = 0; ht < 4; ++ht)
            #pragma unroll
            for (int r = 0; r < 4; ++r) Oa[ht][r] *= alpha[r];

        // ---- P: C-layout -> LDS -> A-layout (per-wave, no barrier needed) --
        #pragma unroll
        for (int nt = 0; nt < 2; ++nt)
            #pragma unroll
            for (int r = 0; r < 4; ++r)
                Pw[wave][(g * 4 + r) * 72 + nt * 16 + n] = f2bf(p[nt][r]);
        const short8 pa = *(const short8*)&Pw[wave][n * 72 + g * 8];

        // ---- PV: O[16 q][64 h] += P[16 x 32] @ V[32 x 64] ------------------
        #pragma unroll
        for (int ht = 0; ht < 4; ++ht) {
            const int h = ht * 16 + n;
            const short8 vf = *(const short8*)((const char*)&Vt[cur][0] + h * 128 +
                                               ((((ks << 2) + g) ^ (h & 7)) << 4));
            Oa[ht] = __builtin_amdgcn_mfma_f32_16x16x32_bf16(pa, vf, Oa[ht], 0, 0, 0);
        }

        // ---- write next tile into the other buffer -------------------------
        if (t + 1 < SS / 64) {
            const int nx = cur ^ 1;
            *(short8*)&Ks[nx][jK0 * 64 + ((cs ^ (jK0 & 7)) << 3)] = kr0;
            *(short8*)&Ks[nx][jK1 * 64 + ((cs ^ (jK1 & 7)) << 3)] = kr1;
            const u16* a0 = (const u16*)&vr0; const u16* a1 = (const u16*)&vr1;
            const u16* a2 = (const u16*)&vr2; const u16* a3 = (const u16*)&vr3;
            #pragma unroll
            for (int i = 0; i < 4; ++i) {
                const int h = hV + i;
                ushort4 w; w.x = a0[i]; w.y = a1[i]; w.z = a2[i]; w.w = a3[i];
                *(ushort4*)((char*)&Vt[nx][0] + h * 128 + (((jV >> 3) ^ (h & 7)) << 4) + ((jV & 4) << 1)) = w;
            }
        }
        __syncthreads();
    }

    // ---- combine the two key-splits via LDS (reuse Ks) ----------------------
    float* Cb = (float*)&Ks[0][0];          // [wq][16][68]
    float* Cm = Cb + 2 * 16 * 68;           // [wq][16]
    float* Cl = Cm + 32;
    if (ks == 1) {
        #pragma unroll
        for (int ht = 0; ht < 4; ++ht)
            #pragma unroll
            for (int r = 0; r < 4; ++r)
                Cb[(wq * 16 + g * 4 + r) * 68 + ht * 16 + n] = Oa[ht][r];
        if (n == 0)
            #pragma unroll
            for (int r = 0; r < 4; ++r) {
                Cm[wq * 16 + g * 4 + r] = m_i[r];
                Cl[wq * 16 + g * 4 + r] = l_i[r];
            }
    }
    __syncthreads();
    if (ks == 0) {
        float a0v[4], a1v[4], linv[4];
        #pragma unroll
        for (int r = 0; r < 4; ++r) {
            const int m = g * 4 + r;
            const float m1 = Cm[wq * 16 + m], l1 = Cl[wq * 16 + m];
            const float M  = fmaxf(m_i[r], m1);
            const float e0 = __expf(m_i[r] - M), e1 = __expf(m1 - M);
            a0v[r] = e0; a1v[r] = e1;
            linv[r] = 1.f / (l_i[r] * e0 + l1 * e1);
        }
        #pragma unroll
        for (int ht = 0; ht < 4; ++ht)
            #pragma unroll
            for (int r = 0; r < 4; ++r) {
                const float o1 = Cb[(wq * 16 + g * 4 + r) * 68 + ht * 16 + n];
                const float v  = (Oa[ht][r] * a0v[r] + o1 * a1v[r]) * linv[r];
                out[((size_t)b * SS + q0 + wq * 16 + g * 4 + r) * HH + ht * 16 + n] = v;
            }
    }
}

// ---------------------------------------------------------------------------
extern "C" void kernel_launch(void* const* d_in, const int* in_sizes, int n_in,
                              void* d_out, int out_size, void* d_ws, size_t ws_size,
                              hipStream_t stream) {
    const float* query = (const float*)d_in[0];
    const float* key   = (const float*)d_in[1];
    const float* value = (const float*)d_in[2];
    const float* Wq    = (const float*)d_in[3];
    const float* bq    = (const float*)d_in[4];
    const float* Wk    = (const float*)d_in[5];
    const float* bk    = (const float*)d_in[6];
    const float* Wv    = (const float*)d_in[7];
    const float* bv    = (const float*)d_in[8];
    float* out = (float*)d_out;

    u16* qp = (u16*)d_ws;                        // 16384 x 64 bf16 each
    u16* kp = qp + (size_t)MM * HH;
    u16* vp = kp + (size_t)MM * HH;

    dim3 pgrid(MM / BMROWS, 3);
    proj_mfma<<<pgrid, 256, 0, stream>>>(query, key, value,
                                         Wq, Wk, Wv,
                                         bq, bk, bv,
                                         qp, kp, vp);

    dim3 agrid(SS / 32, BB);
    flash_mfma<<<agrid, 256, 0, stream>>>(qp, kp, vp, out);
}